// Round 1
// 846.547 us; speedup vs baseline: 3.9950x; 3.9950x over previous
//
#include <hip/hip_runtime.h>

#define T_OBS 512
#define HID   48
#define NTILE 3            // M-tiles per wave (4 waves x 3 = 12 tiles = 192 gate rows)
#define RSTR  232          // halves per batch-row in LDS h-buffer (116 words = 20 mod 32 -> conflict-free b128)

typedef float f32x4  __attribute__((ext_vector_type(4)));
typedef short bf16x8 __attribute__((ext_vector_type(8)));

__device__ __forceinline__ unsigned short f2bf(float f) {
    union { float f; unsigned u; } v; v.f = f;
    unsigned r = v.u + 0x7fffu + ((v.u >> 16) & 1u);   // round-to-nearest-even
    return (unsigned short)(r >> 16);
}
__device__ __forceinline__ float bf2f(unsigned short h) {
    union { unsigned u; float f; } v; v.u = ((unsigned)h) << 16;
    return v.f;
}
__device__ __forceinline__ float sigm(float v) {
    return __builtin_amdgcn_rcpf(1.f + __builtin_amdgcn_exp2f(-1.44269504089f * v));
}
__device__ __forceinline__ float tanh_f(float v) {
    return 1.f - 2.f * __builtin_amdgcn_rcpf(1.f + __builtin_amdgcn_exp2f(2.88539008178f * v));
}

// LDS h-buffer layout per batch-row n (halves index within row):
//   [  0.. 47] h0 buf0   [ 48.. 95] h0 buf1
//   [ 96..143] h1 buf0   [144..191] h1 buf1
//   [208..223] zeros (K-pad for layer0)          row stride RSTR=232
__global__ __launch_bounds__(256, 1) void lstm2_mfma(
    const float* __restrict__ x,
    const float* __restrict__ Wih0, const float* __restrict__ Whh0,
    const float* __restrict__ bih0, const float* __restrict__ bhh0,
    const float* __restrict__ Wih1, const float* __restrict__ Whh1,
    const float* __restrict__ bih1, const float* __restrict__ bhh1,
    const float* __restrict__ Wlin, const float* __restrict__ blin,
    const int* __restrict__ fut,
    float* __restrict__ out)
{
    __shared__ ushort s_hi[16 * RSTR];
    __shared__ ushort s_lo[16 * RSTR];
    __shared__ float  s_pr[16 * 20];   // head partials [n][16], stride 20 for align+banks

    const int tid  = threadIdx.x;
    const int wave = tid >> 6;
    const int lane = tid & 63;
    const int n    = lane & 15;        // batch column (MFMA N / A-row index)
    const int rg   = lane >> 4;        // k-group (and C row-group)

    // zero h buffers (covers t=0 state h=0 and the K-pad region)
    for (int i = tid; i < 16 * RSTR; i += 256) { s_hi[i] = 0; s_lo[i] = 0; }

    // ---- build weight A-fragments in registers (one-time) ----
    // A-frag element: row' = 16*m + (lane&15), k = 32*s + 8*(lane>>4) + j
    // rows permuted: row' = u*4 + g  ->  original row = g*48 + u
    bf16x8 a0hi[NTILE][2], a0lo[NTILE][2];
    bf16x8 a1hi[NTILE][3], a1lo[NTILE][3];
    #pragma unroll
    for (int i = 0; i < NTILE; ++i) {
        const int m  = wave * NTILE + i;
        const int rp = 16 * m + n;
        const int r0 = (rp & 3) * 48 + (rp >> 2);
        #pragma unroll
        for (int s = 0; s < 2; ++s) {
            #pragma unroll
            for (int j = 0; j < 8; ++j) {
                const int k = 32 * s + 8 * rg + j;
                const float w = (k < 48) ? Whh0[r0 * 48 + k] : 0.f;   // zero K-pad 48..63
                const unsigned short hi = f2bf(w);
                a0hi[i][s][j] = (short)hi;
                a0lo[i][s][j] = (short)f2bf(w - bf2f(hi));
            }
        }
        #pragma unroll
        for (int s = 0; s < 3; ++s) {
            #pragma unroll
            for (int j = 0; j < 8; ++j) {
                const int k = 32 * s + 8 * rg + j;                    // K=96 exact: [Wih1 | Whh1]
                const float w = (k < 48) ? Wih1[r0 * 48 + k] : Whh1[r0 * 48 + (k - 48)];
                const unsigned short hi = f2bf(w);
                a1hi[i][s][j] = (short)hi;
                a1lo[i][s][j] = (short)f2bf(w - bf2f(hi));
            }
        }
    }

    // per-lane C-quad constants: u = 4*m + rg, gate g = C reg index
    float b0q[NTILE][4], wi0q[NTILE][4], b1q[NTILE][4], wlq[NTILE];
    int   uq[NTILE];
    #pragma unroll
    for (int i = 0; i < NTILE; ++i) {
        const int u = 4 * (wave * NTILE + i) + rg;
        uq[i]  = u;
        wlq[i] = Wlin[u];
        #pragma unroll
        for (int g = 0; g < 4; ++g) {
            b0q[i][g]  = bih0[g * 48 + u] + bhh0[g * 48 + u];
            b1q[i][g]  = bih1[g * 48 + u] + bhh1[g * 48 + u];
            wi0q[i][g] = Wih0[g * 48 + u];
        }
    }

    const int F    = fut[0];
    const int Ttot = T_OBS + F;
    const int bb0  = blockIdx.x * 16;
    const float bl = blin[0];
    const int xrow = (bb0 + n) * T_OBS;
    const int nb   = n * RSTR;

    float c0[NTILE], c1[NTILE];
    #pragma unroll
    for (int i = 0; i < NTILE; ++i) { c0[i] = 0.f; c1[i] = 0.f; }
    float oprev = 0.f;
    float cur   = x[xrow];

    __syncthreads();

    for (int t = 0; t < Ttot; ++t) {
        const int cb = (t & 1) * 48;    // current-step h sub-buffer
        const int pb = 48 - cb;         // previous-step h sub-buffer

        // prefetch next x; pick this step's input
        const int   tn  = (t + 1 < T_OBS) ? (t + 1) : (T_OBS - 1);
        const float nxt = x[xrow + tn];
        const float inp = (t < T_OBS) ? cur : oprev;

        // ---- layer 0 B-fragments: h0_{t-1} (+ zero pad rows 48..63) ----
        bf16x8 b0h[2], b0l[2];
        #pragma unroll
        for (int s = 0; s < 2; ++s) {
            const int k0 = 32 * s + 8 * rg;
            const int a  = (k0 < 48) ? (nb + pb + k0) : (nb + 208 + (k0 - 48));
            b0h[s] = *(const bf16x8*)(s_hi + a);
            b0l[s] = *(const bf16x8*)(s_lo + a);
        }

        f32x4 acc[NTILE];
        #pragma unroll
        for (int i = 0; i < NTILE; ++i)
            #pragma unroll
            for (int g = 0; g < 4; ++g)
                acc[i][g] = fmaf(inp, wi0q[i][g], b0q[i][g]);

        #pragma unroll
        for (int s = 0; s < 2; ++s)
            #pragma unroll
            for (int i = 0; i < NTILE; ++i) {
                acc[i] = __builtin_amdgcn_mfma_f32_16x16x32_bf16(a0hi[i][s], b0h[s], acc[i], 0, 0, 0);
                acc[i] = __builtin_amdgcn_mfma_f32_16x16x32_bf16(a0lo[i][s], b0h[s], acc[i], 0, 0, 0);
                acc[i] = __builtin_amdgcn_mfma_f32_16x16x32_bf16(a0hi[i][s], b0l[s], acc[i], 0, 0, 0);
            }

        // layer-0 activations; write h0_t (hi/lo) into current buffer
        #pragma unroll
        for (int i = 0; i < NTILE; ++i) {
            const float ig = sigm(acc[i][0]);
            const float fg = sigm(acc[i][1]);
            const float gg = tanh_f(acc[i][2]);
            const float og = sigm(acc[i][3]);
            c0[i] = fg * c0[i] + ig * gg;
            const float h = og * tanh_f(c0[i]);
            const unsigned short hi = f2bf(h);
            s_hi[nb + cb + uq[i]] = hi;
            s_lo[nb + cb + uq[i]] = f2bf(h - bf2f(hi));
        }
        __syncthreads();   // B1: h0_t visible to all waves

        // ---- layer 1 B-fragments: [h0_t ; h1_{t-1}], K = 96 ----
        bf16x8 b1h[3], b1l[3];
        #pragma unroll
        for (int s = 0; s < 3; ++s) {
            const int k0 = 32 * s + 8 * rg;
            const int a  = (k0 < 48) ? (nb + cb + k0) : (nb + 96 + pb + (k0 - 48));
            b1h[s] = *(const bf16x8*)(s_hi + a);
            b1l[s] = *(const bf16x8*)(s_lo + a);
        }

        #pragma unroll
        for (int i = 0; i < NTILE; ++i)
            #pragma unroll
            for (int g = 0; g < 4; ++g)
                acc[i][g] = b1q[i][g];

        #pragma unroll
        for (int s = 0; s < 3; ++s)
            #pragma unroll
            for (int i = 0; i < NTILE; ++i) {
                acc[i] = __builtin_amdgcn_mfma_f32_16x16x32_bf16(a1hi[i][s], b1h[s], acc[i], 0, 0, 0);
                acc[i] = __builtin_amdgcn_mfma_f32_16x16x32_bf16(a1lo[i][s], b1h[s], acc[i], 0, 0, 0);
                acc[i] = __builtin_amdgcn_mfma_f32_16x16x32_bf16(a1hi[i][s], b1l[s], acc[i], 0, 0, 0);
            }

        // layer-1 activations; write h1_t; head partial
        float part = 0.f;
        #pragma unroll
        for (int i = 0; i < NTILE; ++i) {
            const float ig = sigm(acc[i][0]);
            const float fg = sigm(acc[i][1]);
            const float gg = tanh_f(acc[i][2]);
            const float og = sigm(acc[i][3]);
            c1[i] = fg * c1[i] + ig * gg;
            const float h = og * tanh_f(c1[i]);
            const unsigned short hi = f2bf(h);
            s_hi[nb + 96 + cb + uq[i]] = hi;
            s_lo[nb + 96 + cb + uq[i]] = f2bf(h - bf2f(hi));
            part = fmaf(h, wlq[i], part);
        }
        s_pr[n * 20 + wave * 4 + rg] = part;
        __syncthreads();   // B2: h1_t + partials visible

        // head: out[n] = sum of 16 partials + bias (all lanes compute, for oprev)
        const f32x4 p0 = *(const f32x4*)(s_pr + n * 20 + 0);
        const f32x4 p1 = *(const f32x4*)(s_pr + n * 20 + 4);
        const f32x4 p2 = *(const f32x4*)(s_pr + n * 20 + 8);
        const f32x4 p3 = *(const f32x4*)(s_pr + n * 20 + 12);
        const f32x4 ps = p0 + p1 + p2 + p3;
        const float o  = ps[0] + ps[1] + ps[2] + ps[3] + bl;
        if (tid < 16) out[(bb0 + n) * Ttot + t] = o;
        oprev = o;
        cur   = nxt;
    }
}

extern "C" void kernel_launch(void* const* d_in, const int* in_sizes, int n_in,
                              void* d_out, int out_size, void* d_ws, size_t ws_size,
                              hipStream_t stream) {
    const float* x    = (const float*)d_in[0];
    const float* Wih0 = (const float*)d_in[1];
    const float* Whh0 = (const float*)d_in[2];
    const float* bih0 = (const float*)d_in[3];
    const float* bhh0 = (const float*)d_in[4];
    const float* Wih1 = (const float*)d_in[5];
    const float* Whh1 = (const float*)d_in[6];
    const float* bih1 = (const float*)d_in[7];
    const float* bhh1 = (const float*)d_in[8];
    const float* Wlin = (const float*)d_in[9];
    const float* blin = (const float*)d_in[10];
    const int*   fut  = (const int*)d_in[11];
    float* out = (float*)d_out;

    const int B    = in_sizes[0] / T_OBS;   // 4096
    const int grid = B / 16;                // 256 blocks -> 1 per CU
    lstm2_mfma<<<grid, 256, 0, stream>>>(
        x, Wih0, Whh0, bih0, bhh0, Wih1, Whh1, bih1, bhh1, Wlin, blin, fut, out);
}

// Round 2
// 718.448 us; speedup vs baseline: 4.7073x; 1.1783x over previous
//
#include <hip/hip_runtime.h>

#define T_OBS 512
#define NTILE 3            // tiles per wave per layer (4 waves x 3 = 12 tiles = 192 gate rows)
#define RSTR  232          // halves per batch-row: 16B-aligned, quad-stride 29 (odd) -> uniform banks
#define L2E   1.44269504089f

typedef float f32x4  __attribute__((ext_vector_type(4)));
typedef short bf16x8 __attribute__((ext_vector_type(8)));

__device__ __forceinline__ unsigned short f2bf(float f) {
    union { float f; unsigned u; } v; v.f = f;
    unsigned r = v.u + 0x7fffu + ((v.u >> 16) & 1u);   // RNE
    return (unsigned short)(r >> 16);
}
__device__ __forceinline__ float bf2f(unsigned short h) {
    union { unsigned u; float f; } v; v.u = ((unsigned)h) << 16;
    return v.f;
}
// prescaled activations: weights/biases carry the log2e factors
__device__ __forceinline__ float sigm_p(float a) {   // a = -log2e * x
    return __builtin_amdgcn_rcpf(1.f + __builtin_amdgcn_exp2f(a));
}
__device__ __forceinline__ float tanh_p(float a) {   // a = 2*log2e * x
    return 1.f - 2.f * __builtin_amdgcn_rcpf(1.f + __builtin_amdgcn_exp2f(a));
}
__device__ __forceinline__ float tanh_r(float v) {   // real-unit tanh (for cell state)
    return 1.f - 2.f * __builtin_amdgcn_rcpf(1.f + __builtin_amdgcn_exp2f(2.f * L2E * v));
}

// LDS h-buffer per batch-row n (half indices within row, stride RSTR):
//   [0..47] h0 parity0 | [48..95] h0 parity1 | [96..143] h1 parity0 | [144..191] h1 parity1
__global__ __launch_bounds__(256, 1) void lstm2_pipe(
    const float* __restrict__ x,
    const float* __restrict__ Wih0, const float* __restrict__ Whh0,
    const float* __restrict__ bih0, const float* __restrict__ bhh0,
    const float* __restrict__ Wih1, const float* __restrict__ Whh1,
    const float* __restrict__ bih1, const float* __restrict__ bhh1,
    const float* __restrict__ Wlin, const float* __restrict__ blin,
    const int* __restrict__ fut,
    float* __restrict__ out)
{
    __shared__ ushort s_hi[16 * RSTR];
    __shared__ ushort s_lo[16 * RSTR];
    __shared__ __attribute__((aligned(16))) float s_pr[2][64];   // head partials, dbuf by parity

    const int tid  = threadIdx.x;
    const int wave = tid >> 6;
    const int lane = tid & 63;
    const int n    = lane & 15;        // batch column
    const int rg   = lane >> 4;        // k-group / C row-group

    for (int i = tid; i < 16 * RSTR; i += 256) { s_hi[i] = 0; s_lo[i] = 0; }

    // gate of this lane's A-rows: rp = 16m + n -> gate = n&3 (uniform per lane)
    const float sgl = ((n & 3) == 2) ? 2.f * L2E : -L2E;

    // ---- A fragments in registers, prescaled, hi/lo RNE split ----
    bf16x8 a0hi[NTILE][2], a0lo[NTILE][2];
    bf16x8 a1hi[NTILE][3], a1lo[NTILE][3];
    #pragma unroll
    for (int i = 0; i < NTILE; ++i) {
        const int m  = wave * NTILE + i;
        const int rp = 16 * m + n;
        const int r0 = (rp & 3) * 48 + (rp >> 2);      // rows permuted: rp = u*4 + gate
        #pragma unroll
        for (int s = 0; s < 2; ++s)
            #pragma unroll
            for (int j = 0; j < 8; ++j) {
                const int k = 32 * s + 8 * rg + j;
                const float w = (k < 48) ? Whh0[r0 * 48 + k] * sgl : 0.f;   // zero K-pad
                const unsigned short hi = f2bf(w);
                a0hi[i][s][j] = (short)hi;
                a0lo[i][s][j] = (short)f2bf(w - bf2f(hi));
            }
        #pragma unroll
        for (int s = 0; s < 3; ++s)
            #pragma unroll
            for (int j = 0; j < 8; ++j) {
                const int k = 32 * s + 8 * rg + j;                           // K=96: [Wih1|Whh1]
                const float w = ((k < 48) ? Wih1[r0 * 48 + k] : Whh1[r0 * 48 + (k - 48)]) * sgl;
                const unsigned short hi = f2bf(w);
                a1hi[i][s][j] = (short)hi;
                a1lo[i][s][j] = (short)f2bf(w - bf2f(hi));
            }
    }

    const float sg4[4] = { -L2E, -L2E, 2.f * L2E, -L2E };   // (i,f,g,o)
    f32x4 b0v[NTILE], b1v[NTILE], wi0v[NTILE];
    float wlq[NTILE];
    int   sb[NTILE];
    #pragma unroll
    for (int i = 0; i < NTILE; ++i) {
        const int u = 4 * (wave * NTILE + i) + rg;
        sb[i]  = n * RSTR + u;
        wlq[i] = Wlin[u];
        #pragma unroll
        for (int g = 0; g < 4; ++g) {
            b0v[i][g]  = (bih0[g * 48 + u] + bhh0[g * 48 + u]) * sg4[g];
            b1v[i][g]  = (bih1[g * 48 + u] + bhh1[g * 48 + u]) * sg4[g];
            wi0v[i][g] = Wih0[g * 48 + u] * sg4[g];
        }
    }

    // B-fragment k-offsets (shared by both layers: L0's pad cols have zero weights)
    int koff[3];
    #pragma unroll
    for (int s = 0; s < 3; ++s) {
        const int k0 = 32 * s + 8 * rg;
        koff[s] = (k0 < 48) ? k0 : k0 + 48;   // k>=48 -> h1 region (+96 base, -48 k)
    }

    const int F    = fut[0];
    const int TT   = T_OBS + F;
    const int bb0  = blockIdx.x * 16;
    const float bl = blin[0];
    const int xrow = (bb0 + n) * T_OBS;
    const int nb   = n * RSTR;

    float c0[NTILE], c1[NTILE];
    #pragma unroll
    for (int i = 0; i < NTILE; ++i) { c0[i] = 0.f; c1[i] = 0.f; }

    __syncthreads();

    const f32x4 z4 = { 0.f, 0.f, 0.f, 0.f };

    // tick tau: L0 computes step tau (tau<TT); L1 computes step tau-1 (tau>=1).
    // Both read only parity (tau-1)&1 state; write parity tau&1. One barrier/tick.
    for (int tau = 0; tau <= TT; ++tau) {
        const int cb = (tau & 1) * 48;
        const int pb = 48 - cb;
        const bool ar = (tau >= T_OBS);

        const float xin = (tau < T_OBS) ? x[xrow + tau] : 0.f;

        // deferred head output: o_{tau-2} from s_pr written last tick
        if (tau >= 2 && tau <= T_OBS && tid < 16) {
            const f32x4 p = *(const f32x4*)(&s_pr[(tau - 1) & 1][tid * 4]);
            out[(bb0 + tid) * TT + (tau - 2)] = p[0] + p[1] + p[2] + p[3] + bl;
        }

        // ---- B fragments (shared L0/L1): h0_{tau-1}, h1_{tau-2} ----
        const int rb = nb + pb;
        bf16x8 bh[3], bw[3];
        #pragma unroll
        for (int s = 0; s < 3; ++s) {
            bh[s] = *(const bf16x8*)(s_hi + rb + koff[s]);
            bw[s] = *(const bf16x8*)(s_lo + rb + koff[s]);
        }

        // ---- 45 MFMAs, 15 independent depth-3 chains, biases as C-in ----
        f32x4 p0[NTILE], p0s[NTILE], p1[NTILE], p1s[NTILE], p1t[NTILE];
        #pragma unroll
        for (int i = 0; i < NTILE; ++i) {
            p0[i]  = __builtin_amdgcn_mfma_f32_16x16x32_bf16(a0hi[i][0], bh[0], b0v[i], 0, 0, 0);
            p0[i]  = __builtin_amdgcn_mfma_f32_16x16x32_bf16(a0lo[i][0], bh[0], p0[i],  0, 0, 0);
            p0[i]  = __builtin_amdgcn_mfma_f32_16x16x32_bf16(a0hi[i][0], bw[0], p0[i],  0, 0, 0);
            p0s[i] = __builtin_amdgcn_mfma_f32_16x16x32_bf16(a0hi[i][1], bh[1], z4,     0, 0, 0);
            p0s[i] = __builtin_amdgcn_mfma_f32_16x16x32_bf16(a0lo[i][1], bh[1], p0s[i], 0, 0, 0);
            p0s[i] = __builtin_amdgcn_mfma_f32_16x16x32_bf16(a0hi[i][1], bw[1], p0s[i], 0, 0, 0);
            p1[i]  = __builtin_amdgcn_mfma_f32_16x16x32_bf16(a1hi[i][0], bh[0], b1v[i], 0, 0, 0);
            p1[i]  = __builtin_amdgcn_mfma_f32_16x16x32_bf16(a1lo[i][0], bh[0], p1[i],  0, 0, 0);
            p1[i]  = __builtin_amdgcn_mfma_f32_16x16x32_bf16(a1hi[i][0], bw[0], p1[i],  0, 0, 0);
            p1s[i] = __builtin_amdgcn_mfma_f32_16x16x32_bf16(a1hi[i][1], bh[1], z4,     0, 0, 0);
            p1s[i] = __builtin_amdgcn_mfma_f32_16x16x32_bf16(a1lo[i][1], bh[1], p1s[i], 0, 0, 0);
            p1s[i] = __builtin_amdgcn_mfma_f32_16x16x32_bf16(a1hi[i][1], bw[1], p1s[i], 0, 0, 0);
            p1t[i] = __builtin_amdgcn_mfma_f32_16x16x32_bf16(a1hi[i][2], bh[2], z4,     0, 0, 0);
            p1t[i] = __builtin_amdgcn_mfma_f32_16x16x32_bf16(a1lo[i][2], bh[2], p1t[i], 0, 0, 0);
            p1t[i] = __builtin_amdgcn_mfma_f32_16x16x32_bf16(a1hi[i][2], bw[2], p1t[i], 0, 0, 0);
        }

        // ---- layer 1 acts (step tau-1): c1, h1 write, head partial ----
        if (tau >= 1) {
            float part = 0.f;
            #pragma unroll
            for (int i = 0; i < NTILE; ++i) {
                const f32x4 a = p1[i] + p1s[i] + p1t[i];
                const float ig = sigm_p(a[0]);
                const float fg = sigm_p(a[1]);
                const float gg = tanh_p(a[2]);
                const float og = sigm_p(a[3]);
                c1[i] = fg * c1[i] + ig * gg;
                const float h = og * tanh_r(c1[i]);
                const int ad = sb[i] + 96 + cb;
                const unsigned hu = __float_as_uint(h);
                s_hi[ad] = (ushort)(hu >> 16);                       // trunc hi (d16_hi store)
                const float r = h - __uint_as_float(hu & 0xffff0000u);
                s_lo[ad] = (ushort)(__float_as_uint(r) >> 16);
                part = fmaf(h, wlq[i], part);
            }
            part += __shfl_xor(part, 16);
            part += __shfl_xor(part, 32);
            if (lane < 16) s_pr[tau & 1][lane * 4 + wave] = part;
        }

        // ---- input resolve (AR ticks need o_{tau-1} same-tick) ----
        float inp;
        if (ar) {
            __syncthreads();
            const f32x4 p = *(const f32x4*)(&s_pr[tau & 1][n * 4]);
            const float o = p[0] + p[1] + p[2] + p[3] + bl;
            if (tid < 16) out[(bb0 + n) * TT + (tau - 1)] = o;
            inp = o;
        } else {
            inp = xin;
        }

        // ---- layer 0 acts (step tau): rank-1 input term added post-MFMA ----
        if (tau < TT) {
            #pragma unroll
            for (int i = 0; i < NTILE; ++i) {
                f32x4 a = p0[i] + p0s[i];
                a += wi0v[i] * inp;
                const float ig = sigm_p(a[0]);
                const float fg = sigm_p(a[1]);
                const float gg = tanh_p(a[2]);
                const float og = sigm_p(a[3]);
                c0[i] = fg * c0[i] + ig * gg;
                const float h = og * tanh_r(c0[i]);
                const int ad = sb[i] + cb;
                const unsigned hu = __float_as_uint(h);
                s_hi[ad] = (ushort)(hu >> 16);
                const float r = h - __uint_as_float(hu & 0xffff0000u);
                s_lo[ad] = (ushort)(__float_as_uint(r) >> 16);
            }
        }
        __syncthreads();
    }
}

extern "C" void kernel_launch(void* const* d_in, const int* in_sizes, int n_in,
                              void* d_out, int out_size, void* d_ws, size_t ws_size,
                              hipStream_t stream) {
    const float* x    = (const float*)d_in[0];
    const float* Wih0 = (const float*)d_in[1];
    const float* Whh0 = (const float*)d_in[2];
    const float* bih0 = (const float*)d_in[3];
    const float* bhh0 = (const float*)d_in[4];
    const float* Wih1 = (const float*)d_in[5];
    const float* Whh1 = (const float*)d_in[6];
    const float* bih1 = (const float*)d_in[7];
    const float* bhh1 = (const float*)d_in[8];
    const float* Wlin = (const float*)d_in[9];
    const float* blin = (const float*)d_in[10];
    const int*   fut  = (const int*)d_in[11];
    float* out = (float*)d_out;

    const int B    = in_sizes[0] / T_OBS;   // 4096
    const int grid = B / 16;                // 256 blocks -> 1 per CU
    lstm2_pipe<<<grid, 256, 0, stream>>>(
        x, Wih0, Whh0, bih0, bhh0, Wih1, Whh1, bih1, bhh1, Wlin, blin, fut, out);
}

// Round 3
// 618.553 us; speedup vs baseline: 5.4676x; 1.1615x over previous
//
#include <hip/hip_runtime.h>

#define T_OBS 512
#define NTILE 3            // tiles per wave (4 L0-waves x 3 = 12 L0 tiles; 4 L1-waves x 3 = 12 L1 tiles)
#define RSTR  232          // halves per batch-row in LDS h-buffer (16B-aligned rows)
#define L2E   1.44269504089f

typedef float f32x4  __attribute__((ext_vector_type(4)));
typedef short bf16x8 __attribute__((ext_vector_type(8)));

#define MF(A,B,C) __builtin_amdgcn_mfma_f32_16x16x32_bf16(A, B, C, 0, 0, 0)

__device__ __forceinline__ unsigned short f2bf(float f) {
    union { float f; unsigned u; } v; v.f = f;
    unsigned r = v.u + 0x7fffu + ((v.u >> 16) & 1u);   // RNE
    return (unsigned short)(r >> 16);
}
__device__ __forceinline__ float bf2f(unsigned short h) {
    union { unsigned u; float f; } v; v.u = ((unsigned)h) << 16;
    return v.f;
}
// prescaled activations: weights/biases carry the log2e factors
__device__ __forceinline__ float sigm_p(float a) {   // a = -log2e * x
    return __builtin_amdgcn_rcpf(1.f + __builtin_amdgcn_exp2f(a));
}
__device__ __forceinline__ float tanh_p(float a) {   // a = 2*log2e * x
    return 1.f - 2.f * __builtin_amdgcn_rcpf(1.f + __builtin_amdgcn_exp2f(a));
}
__device__ __forceinline__ float tanh_r(float v) {   // real-unit tanh (cell state)
    return 1.f - 2.f * __builtin_amdgcn_rcpf(1.f + __builtin_amdgcn_exp2f(2.f * L2E * v));
}
__device__ __forceinline__ float lstm_act(const f32x4 a, float& c) {
    const float ig = sigm_p(a[0]);
    const float fg = sigm_p(a[1]);
    const float gg = tanh_p(a[2]);
    const float og = sigm_p(a[3]);
    c = fg * c + ig * gg;
    return og * tanh_r(c);
}
__device__ __forceinline__ void store_h(ushort* hi, ushort* lo, int ad, float h) {
    const unsigned hu = __float_as_uint(h);
    hi[ad] = (ushort)(hu >> 16);                               // trunc hi
    const float r = h - __uint_as_float(hu & 0xffff0000u);
    lo[ad] = (ushort)(__float_as_uint(r) >> 16);
}

// LDS h-buffer per batch-row n (half indices within row, stride RSTR):
//   [0..47] h0 par0 | [48..95] h0 par1 | [96..143] h1 par0 | [144..191] h1 par1
__global__ __launch_bounds__(512, 1) void lstm2_split(
    const float* __restrict__ x,
    const float* __restrict__ Wih0, const float* __restrict__ Whh0,
    const float* __restrict__ bih0, const float* __restrict__ bhh0,
    const float* __restrict__ Wih1, const float* __restrict__ Whh1,
    const float* __restrict__ bih1, const float* __restrict__ bhh1,
    const float* __restrict__ Wlin, const float* __restrict__ blin,
    const int* __restrict__ fut,
    float* __restrict__ out)
{
    __shared__ ushort s_hi[16 * RSTR];
    __shared__ ushort s_lo[16 * RSTR];
    __shared__ __attribute__((aligned(16))) float s_pr[2][64];   // head partials, dbuf by parity

    const int tid  = threadIdx.x;
    const int wave = tid >> 6;
    const int lane = tid & 63;
    const int n    = lane & 15;        // batch column
    const int rg   = lane >> 4;        // k-group / C row-group
    const bool isL1 = (wave >= 4);     // waves 0-3: layer 0; waves 4-7: layer 1
    const int  w    = wave & 3;        // role-local wave index

    for (int i = tid; i < 16 * RSTR; i += 512) { s_hi[i] = 0; s_lo[i] = 0; }

    // gate of this lane's A-rows: rp = 16m + n -> gate = n&3 (uniform per lane)
    const float sgl = ((n & 3) == 2) ? 2.f * L2E : -L2E;

    // ---- A fragments in registers, prescaled, hi/lo RNE split ----
    // L0-wave: s=0,1 cover K=64 (zero-padded past 48); L1-wave: s=0..2 cover K=96 [Wih1|Whh1]
    bf16x8 ah[NTILE][3], al[NTILE][3];
    #pragma unroll
    for (int i = 0; i < NTILE; ++i) {
        const int m  = 3 * w + i;
        const int rp = 16 * m + n;
        const int r0 = (rp & 3) * 48 + (rp >> 2);      // rows permuted: rp = u*4 + gate
        #pragma unroll
        for (int s = 0; s < 3; ++s)
            #pragma unroll
            for (int j = 0; j < 8; ++j) {
                const int k = 32 * s + 8 * rg + j;
                float v;
                if (isL1) v = ((k < 48) ? Wih1[r0 * 48 + k] : Whh1[r0 * 48 + (k - 48)]) * sgl;
                else      v = (s < 2 && k < 48) ? Whh0[r0 * 48 + k] * sgl : 0.f;
                const unsigned short hi = f2bf(v);
                ah[i][s][j] = (short)hi;
                al[i][s][j] = (short)f2bf(v - bf2f(hi));
            }
    }

    const float sg4[4] = { -L2E, -L2E, 2.f * L2E, -L2E };   // (i,f,g,o)
    f32x4 bv[NTILE], wi0v[NTILE];
    float wlq[NTILE];
    int   sb[NTILE];
    #pragma unroll
    for (int i = 0; i < NTILE; ++i) {
        const int u = 4 * (3 * w + i) + rg;
        sb[i]  = n * RSTR + u;
        wlq[i] = Wlin[u];
        #pragma unroll
        for (int g = 0; g < 4; ++g) {
            bv[i][g]   = (isL1 ? (bih1[g * 48 + u] + bhh1[g * 48 + u])
                               : (bih0[g * 48 + u] + bhh0[g * 48 + u])) * sg4[g];
            wi0v[i][g] = Wih0[g * 48 + u] * sg4[g];
        }
    }

    // B-fragment k-offsets (shared by both layers: L0's extra cols have zero weights)
    int koff[3];
    #pragma unroll
    for (int s = 0; s < 3; ++s) {
        const int k0 = 32 * s + 8 * rg;
        koff[s] = (k0 < 48) ? k0 : k0 + 48;   // k>=48 -> h1 region (+96 base, -48 k)
    }

    const int F    = fut[0];
    const int TT   = T_OBS + F;
    const int bb0  = blockIdx.x * 16;
    const float bl = blin[0];
    const int xrow = (bb0 + n) * T_OBS;
    const int nb   = n * RSTR;

    float cc[NTILE];
    #pragma unroll
    for (int i = 0; i < NTILE; ++i) cc[i] = 0.f;

    __syncthreads();

    // ---- tick 0 (peeled): L0 step 0 with h0(-1)=0 -> gates = bias + wi0*x0 ----
    if (!isL1) {
        const float x0 = x[xrow];
        #pragma unroll
        for (int i = 0; i < NTILE; ++i) {
            const f32x4 a = bv[i] + wi0v[i] * x0;
            const float h = lstm_act(a, cc[i]);
            store_h(s_hi, s_lo, sb[i] + 0, h);          // cb(0)=0
        }
    }
    __syncthreads();

    // ---- steady loop: tau = 1..511; L0 computes step tau, L1 computes step tau-1 ----
    for (int tau = 1; tau < T_OBS; ++tau) {
        const int cb = (tau & 1) * 48;
        const int pb = 48 - cb;
        const int rb = nb + pb;

        if (!isL1) {
            // deferred head output o(tau-2) (wave 0 lanes only)
            if (tau >= 2 && tid < 16) {
                const f32x4 p = *(const f32x4*)(&s_pr[(tau - 1) & 1][tid * 4]);
                out[(bb0 + tid) * TT + (tau - 2)] = p[0] + p[1] + p[2] + p[3] + bl;
            }
            const bf16x8 bh0 = *(const bf16x8*)(s_hi + rb + koff[0]);
            const bf16x8 bw0 = *(const bf16x8*)(s_lo + rb + koff[0]);
            const bf16x8 bh1 = *(const bf16x8*)(s_hi + rb + koff[1]);
            const bf16x8 bw1 = *(const bf16x8*)(s_lo + rb + koff[1]);
            const float inp = x[xrow + tau];
            #pragma unroll
            for (int i = 0; i < NTILE; ++i) {
                f32x4 a = MF(ah[i][0], bh0, bv[i]);
                a = MF(al[i][0], bh0, a);
                a = MF(ah[i][0], bw0, a);
                a = MF(ah[i][1], bh1, a);
                a = MF(al[i][1], bh1, a);
                a = MF(ah[i][1], bw1, a);
                a += wi0v[i] * inp;
                const float h = lstm_act(a, cc[i]);
                store_h(s_hi, s_lo, sb[i] + cb, h);
            }
        } else {
            bf16x8 bh[3], bw[3];
            #pragma unroll
            for (int s = 0; s < 3; ++s) {
                bh[s] = *(const bf16x8*)(s_hi + rb + koff[s]);
                bw[s] = *(const bf16x8*)(s_lo + rb + koff[s]);
            }
            float part = 0.f;
            #pragma unroll
            for (int i = 0; i < NTILE; ++i) {
                f32x4 a = MF(ah[i][0], bh[0], bv[i]);
                a = MF(al[i][0], bh[0], a);
                a = MF(ah[i][0], bw[0], a);
                a = MF(ah[i][1], bh[1], a);
                a = MF(al[i][1], bh[1], a);
                a = MF(ah[i][1], bw[1], a);
                a = MF(ah[i][2], bh[2], a);
                a = MF(al[i][2], bh[2], a);
                a = MF(ah[i][2], bw[2], a);
                const float h = lstm_act(a, cc[i]);
                store_h(s_hi, s_lo, sb[i] + 96 + cb, h);
                part = fmaf(h, wlq[i], part);
            }
            part += __shfl_xor(part, 16);
            part += __shfl_xor(part, 32);
            if (lane < 16) s_pr[tau & 1][lane * 4 + w] = part;
        }
        __syncthreads();
    }

    // bridge: out(510) from s_pr parity 1 (written at tau=511)
    if (tid < 16) {
        const f32x4 p = *(const f32x4*)(&s_pr[1][tid * 4]);
        out[(bb0 + tid) * TT + (T_OBS - 2)] = p[0] + p[1] + p[2] + p[3] + bl;
    }

    // ---- AR loop: tau = 512..TT; o(tau-1) resolved mid-tick ----
    for (int tau = T_OBS; tau <= TT; ++tau) {
        const int cb = (tau & 1) * 48;
        const int pb = 48 - cb;
        const int rb = nb + pb;

        f32x4 g[NTILE];
        if (isL1) {
            bf16x8 bh[3], bw[3];
            #pragma unroll
            for (int s = 0; s < 3; ++s) {
                bh[s] = *(const bf16x8*)(s_hi + rb + koff[s]);
                bw[s] = *(const bf16x8*)(s_lo + rb + koff[s]);
            }
            float part = 0.f;
            #pragma unroll
            for (int i = 0; i < NTILE; ++i) {
                f32x4 a = MF(ah[i][0], bh[0], bv[i]);
                a = MF(al[i][0], bh[0], a);
                a = MF(ah[i][0], bw[0], a);
                a = MF(ah[i][1], bh[1], a);
                a = MF(al[i][1], bh[1], a);
                a = MF(ah[i][1], bw[1], a);
                a = MF(ah[i][2], bh[2], a);
                a = MF(al[i][2], bh[2], a);
                a = MF(ah[i][2], bw[2], a);
                const float h = lstm_act(a, cc[i]);
                store_h(s_hi, s_lo, sb[i] + 96 + cb, h);
                part = fmaf(h, wlq[i], part);
            }
            part += __shfl_xor(part, 16);
            part += __shfl_xor(part, 32);
            if (lane < 16) s_pr[tau & 1][lane * 4 + w] = part;
        } else {
            const bf16x8 bh0 = *(const bf16x8*)(s_hi + rb + koff[0]);
            const bf16x8 bw0 = *(const bf16x8*)(s_lo + rb + koff[0]);
            const bf16x8 bh1 = *(const bf16x8*)(s_hi + rb + koff[1]);
            const bf16x8 bw1 = *(const bf16x8*)(s_lo + rb + koff[1]);
            #pragma unroll
            for (int i = 0; i < NTILE; ++i) {
                f32x4 a = MF(ah[i][0], bh0, bv[i]);
                a = MF(al[i][0], bh0, a);
                a = MF(ah[i][0], bw0, a);
                a = MF(ah[i][1], bh1, a);
                a = MF(al[i][1], bh1, a);
                a = MF(ah[i][1], bw1, a);
                g[i] = a;
            }
        }
        __syncthreads();   // mid: s_pr (h1(tau-1) partials) ready

        if (!isL1) {
            const f32x4 p = *(const f32x4*)(&s_pr[tau & 1][n * 4]);
            const float o = p[0] + p[1] + p[2] + p[3] + bl;
            if (tid < 16) out[(bb0 + n) * TT + (tau - 1)] = o;
            if (tau < TT) {
                #pragma unroll
                for (int i = 0; i < NTILE; ++i) {
                    f32x4 a = g[i] + wi0v[i] * o;
                    const float h = lstm_act(a, cc[i]);
                    store_h(s_hi, s_lo, sb[i] + cb, h);
                }
            }
        }
        __syncthreads();
    }
}

extern "C" void kernel_launch(void* const* d_in, const int* in_sizes, int n_in,
                              void* d_out, int out_size, void* d_ws, size_t ws_size,
                              hipStream_t stream) {
    const float* x    = (const float*)d_in[0];
    const float* Wih0 = (const float*)d_in[1];
    const float* Whh0 = (const float*)d_in[2];
    const float* bih0 = (const float*)d_in[3];
    const float* bhh0 = (const float*)d_in[4];
    const float* Wih1 = (const float*)d_in[5];
    const float* Whh1 = (const float*)d_in[6];
    const float* bih1 = (const float*)d_in[7];
    const float* bhh1 = (const float*)d_in[8];
    const float* Wlin = (const float*)d_in[9];
    const float* blin = (const float*)d_in[10];
    const int*   fut  = (const int*)d_in[11];
    float* out = (float*)d_out;

    const int B    = in_sizes[0] / T_OBS;   // 4096
    const int grid = B / 16;                // 256 blocks -> 1 per CU, 8 waves = 2/SIMD
    lstm2_split<<<grid, 512, 0, stream>>>(
        x, Wih0, Whh0, bih0, bhh0, Wih1, Whh1, bih1, bhh1, Wlin, blin, fut, out);
}